// Round 8
// baseline (504.111 us; speedup 1.0000x reference)
//
#include <hip/hip_runtime.h>
#include <math.h>

#define EPS 1e-5f

typedef __attribute__((ext_vector_type(8)))  _Float16 half8;   // 8 f16 (4 VGPR)
typedef __attribute__((ext_vector_type(16))) float    floatx16;

__device__ __forceinline__ unsigned short f2h_bits(float f) {
    _Float16 h = (_Float16)f;
    return __builtin_bit_cast(unsigned short, h);
}

// ---------------------------------------------------------------------------
// Prepass A: data[N][32] fp32 -> 4 channel-group tables dpk4[g][N][8] f16.
// Each group table = N*16 B = 4.8 MB  (~ one XCD's 4 MB L2 -> L2-resident
// during pass g of the deconv; that's the whole point of this round).
// grid (ceil(N/256), 4): coalesced 16 B writes within a group.
// ---------------------------------------------------------------------------
__global__ __launch_bounds__(256) void pack_data_kernel(
    const float* __restrict__ data, unsigned short* __restrict__ dpk4, int N)
{
    const int n = blockIdx.x * 256 + threadIdx.x;
    const int g = blockIdx.y;
    if (n >= N) return;
    const float4 v0 = *(const float4*)(data + (size_t)n * 32 + g * 8);
    const float4 v1 = *(const float4*)(data + (size_t)n * 32 + g * 8 + 4);
    ushort4 o0, o1;
    o0.x = f2h_bits(v0.x); o0.y = f2h_bits(v0.y);
    o0.z = f2h_bits(v0.z); o0.w = f2h_bits(v0.w);
    o1.x = f2h_bits(v1.x); o1.y = f2h_bits(v1.y);
    o1.z = f2h_bits(v1.z); o1.w = f2h_bits(v1.w);
    unsigned short* row = dpk4 + (size_t)g * N * 8 + (size_t)n * 8;
    *(ushort4*)(row)     = o0;
    *(ushort4*)(row + 4) = o1;
}

// ---------------------------------------------------------------------------
// Prepass B: W -> B-fragments for the 2-taps-per-MFMA scheme.
// Logical K of MFMA pair p, group g: k=0..7 -> (tap 2p,  ci 8g+k)
//                                    k=8..15 -> (tap 2p+1, ci 8g+k-8)
// B[k][n]: lane l holds n=l&31, k=8*(l>>5)+j  ->  W[2p+(l>>5)][8g+j][n].
// Tap 27 (pair 13, odd half) is zero. Layout: wpk[((g*14+p)*64+l)*8+j].
// grid (14, 4) x 64 threads.
// ---------------------------------------------------------------------------
__global__ __launch_bounds__(64) void pack_w_kernel(
    const float* __restrict__ W, unsigned short* __restrict__ wpk)
{
    const int l = threadIdx.x;
    const int p = blockIdx.x;
    const int g = blockIdx.y;
    const int n   = l & 31;
    const int tap = 2 * p + (l >> 5);
    ushort4 o0 = make_ushort4(0, 0, 0, 0), o1 = o0;
    if (tap < 27) {
        const float* wp = W + tap * 1024 + g * 8 * 32 + n;
        o0.x = f2h_bits(wp[0 * 32]);
        o0.y = f2h_bits(wp[1 * 32]);
        o0.z = f2h_bits(wp[2 * 32]);
        o0.w = f2h_bits(wp[3 * 32]);
        o1.x = f2h_bits(wp[4 * 32]);
        o1.y = f2h_bits(wp[5 * 32]);
        o1.z = f2h_bits(wp[6 * 32]);
        o1.w = f2h_bits(wp[7 * 32]);
    }
    unsigned short* dst = wpk + ((size_t)(g * 14 + p) * 64 + l) * 8;
    *(ushort4*)(dst)     = o0;
    *(ushort4*)(dst + 4) = o1;
}

// ---------------------------------------------------------------------------
// Deconv via f16 MFMA, channel-split into 4 L2-resident passes + GN stats.
// Block = 256 = 4 waves; wave = 32 nodes x 32 couts (one 32x32 acc).
// Pass g: stage 14.3 KB of B in LDS (cooperative, 2 barriers), issue ALL 14
// gather loads (16 B/lane, from the 4.8 MB group table -> L2 hits), then 14
// MFMAs. Neighbor indices: 14 per lane, loaded once. All register arrays
// fully unrolled (compile-time indices only -- round-3 scratch lesson).
// ---------------------------------------------------------------------------
__global__ __launch_bounds__(256) void deconv_stats_kernel(
    const unsigned short* __restrict__ dpk4, const unsigned short* __restrict__ wpk,
    const int* __restrict__ neigh, const int* __restrict__ batch_id,
    float* __restrict__ out, float* __restrict__ gs1, float* __restrict__ gs2,
    float* __restrict__ gcnt, int N)
{
    __shared__ unsigned short BW[14 * 64 * 8];     // 14336 B
    __shared__ float ls1[256];
    __shared__ float ls2[256];
    __shared__ float lcnt[8];

    const int t    = threadIdx.x;
    const int wv   = t >> 6;
    const int l    = t & 63;
    const int mrow = l & 31;
    const int par  = l >> 5;
    const int wbase = blockIdx.x * 128 + wv * 32;
    const int node  = (wbase + mrow) < N ? (wbase + mrow) : (N - 1);

    // per-lane neighbor indices for its 14 (pair, parity) slots
    int nb[14];
    {
        const int* nrow = neigh + (size_t)node * 27;
#pragma unroll
        for (int p = 0; p < 14; ++p) {
            int tap = 2 * p + par;
            if (tap > 26) tap = 26;                // pair-13 odd half: B==0
            nb[p] = nrow[tap];
        }
    }

    ls1[t] = 0.f;
    ls2[t] = 0.f;
    if (t < 8) lcnt[t] = 0.f;

    floatx16 acc;
#pragma unroll
    for (int r = 0; r < 16; ++r) acc[r] = 0.f;

#pragma unroll 1
    for (int g = 0; g < 4; ++g) {
        __syncthreads();                           // prev pass's B consumed
        // stage group g's B fragments: 896 int4
        {
            const int4* src = (const int4*)(wpk + (size_t)g * 7168);
#pragma unroll
            for (int r = 0; r < 4; ++r) {
                const int i = r * 256 + t;
                if (i < 896) ((int4*)BW)[i] = src[i];
            }
        }
        __syncthreads();

        const unsigned short* dg = dpk4 + (size_t)g * N * 8;

        // issue all 14 gathers (16 B each, L2-resident group table)
        half8 a[14];
#pragma unroll
        for (int p = 0; p < 14; ++p)
            a[p] = *(const half8*)(dg + (size_t)nb[p] * 8);

        // consume in order: ds_read B + MFMA (2 taps per MFMA)
#pragma unroll
        for (int p = 0; p < 14; ++p) {
            const half8 b = *(const half8*)(BW + (size_t)(p * 64 + l) * 8);
            acc = __builtin_amdgcn_mfma_f32_32x32x16_f16(a[p], b, acc, 0, 0, 0);
        }
    }

    // ---- epilogue (proven): C layout col=l&31, row=(r&3)+8*(r>>2)+4*par ----
    const int co = mrow;
#pragma unroll
    for (int r = 0; r < 16; ++r) {
        const int row = (r & 3) + 8 * (r >> 2) + 4 * par;
        const int n = wbase + row;
        if (n < N) out[(size_t)n * 32 + co] = acc[r];
    }

    bool fast = (wbase + 31 < N);
    int bfst = 0;
    if (fast) {
        bfst = batch_id[wbase];
        fast = (bfst == batch_id[wbase + 31]);
    }
    if (fast) {
        float s1 = 0.f, s2 = 0.f;
#pragma unroll
        for (int r = 0; r < 16; ++r) {
            const float v = acc[r];
            s1 += v;
            s2 += v * v;
        }
        atomicAdd(&ls1[bfst * 32 + co], s1);
        atomicAdd(&ls2[bfst * 32 + co], s2);
    } else {
#pragma unroll
        for (int r = 0; r < 16; ++r) {
            const int row = (r & 3) + 8 * (r >> 2) + 4 * par;
            const int n = wbase + row;
            if (n < N) {
                const int b = batch_id[n];
                const float v = acc[r];
                atomicAdd(&ls1[b * 32 + co], v);
                atomicAdd(&ls2[b * 32 + co], v * v);
            }
        }
    }
    if (par == 0) {
        const int n = wbase + mrow;
        if (n < N) atomicAdd(&lcnt[batch_id[n]], 1.0f);
    }
    __syncthreads();

    {
        float v;
        v = ls1[t]; if (v != 0.f) atomicAdd(&gs1[t], v);
        v = ls2[t]; if (v != 0.f) atomicAdd(&gs2[t], v);
        if (t < 8) { v = lcnt[t]; if (v != 0.f) atomicAdd(&gcnt[t], v); }
    }
}

// ---------------------------------------------------------------------------
// GN finalize + apply + ReLU (unchanged, proven)
// ---------------------------------------------------------------------------
__global__ __launch_bounds__(256) void gn_relu_kernel(
    float* __restrict__ out, const int* __restrict__ batch_id,
    const float* __restrict__ gs1, const float* __restrict__ gs2,
    const float* __restrict__ gcnt, const float* __restrict__ gamma,
    const float* __restrict__ beta, int N)
{
    const int idx = blockIdx.x * 256 + threadIdx.x;
    if (idx >= N * 8) return;
    const int n = idx >> 3;
    const int g = idx & 7;
    const int b = batch_id[n];

    const float cnt  = gcnt[b] * 4.0f;
    const float icnt = 1.0f / (cnt + EPS);
    const float4 s1 = *(const float4*)(gs1 + b * 32 + g * 4);
    const float4 s2 = *(const float4*)(gs2 + b * 32 + g * 4);
    const float S1 = s1.x + s1.y + s1.z + s1.w;
    const float S2 = s2.x + s2.y + s2.z + s2.w;
    const float m   = S1 * icnt;
    const float var = (S2 - 2.0f * m * S1 + cnt * m * m) * icnt;
    const float istd = rsqrtf(var + EPS);

    const float4 gm4 = *(const float4*)(gamma + g * 4);
    const float4 bt4 = *(const float4*)(beta + g * 4);
    float4 h = *(float4*)(out + (size_t)idx * 4);
    h.x = fmaxf((h.x - m) * istd * gm4.x + bt4.x, 0.f);
    h.y = fmaxf((h.y - m) * istd * gm4.y + bt4.y, 0.f);
    h.z = fmaxf((h.z - m) * istd * gm4.z + bt4.z, 0.f);
    h.w = fmaxf((h.w - m) * istd * gm4.w + bt4.w, 0.f);
    *(float4*)(out + (size_t)idx * 4) = h;
}

// ---------------------------------------------------------------------------
extern "C" void kernel_launch(void* const* d_in, const int* in_sizes, int n_in,
                              void* d_out, int out_size, void* d_ws, size_t ws_size,
                              hipStream_t stream) {
    const float* data     = (const float*)d_in[0];   // [N,32]
    const float* weights  = (const float*)d_in[1];   // [27,32,32]
    const float* gamma    = (const float*)d_in[2];   // [32]
    const float* beta     = (const float*)d_in[3];   // [32]
    const int*   neigh    = (const int*)d_in[4];     // [N,27]
    const int*   batch_id = (const int*)d_in[5];     // [N]
    const int N = in_sizes[0] / 32;
    float* out = (float*)d_out;

    // ws layout (bytes):
    //   [0, 2080)        : gs1[256] gs2[256] gcnt[8]
    //   [4096, +N*64)    : dpk4 (4 groups x N x 8 f16)
    //   [.., +57344)     : wpk  (4 groups x 14 pairs x 64 lanes x 8 f16)
    char* wsb = (char*)d_ws;
    float* gs1  = (float*)wsb;
    float* gs2  = gs1 + 256;
    float* gcnt = gs1 + 512;
    unsigned short* dpk4 = (unsigned short*)(wsb + 4096);
    unsigned short* wpk  = (unsigned short*)(wsb + 4096 + (size_t)N * 64);

    hipMemsetAsync(wsb, 0, 520 * sizeof(float), stream);

    hipLaunchKernelGGL(pack_data_kernel, dim3((N + 255) / 256, 4), dim3(256),
                       0, stream, data, dpk4, N);
    hipLaunchKernelGGL(pack_w_kernel, dim3(14, 4), dim3(64), 0, stream,
                       weights, wpk);

    const int nblocks = (N + 127) / 128;
    hipLaunchKernelGGL(deconv_stats_kernel, dim3(nblocks), dim3(256), 0, stream,
                       dpk4, wpk, neigh, batch_id, out, gs1, gs2, gcnt, N);

    const int n8 = N * 8;
    hipLaunchKernelGGL(gn_relu_kernel, dim3((n8 + 255) / 256), dim3(256), 0,
                       stream, out, batch_id, gs1, gs2, gcnt, gamma, beta, N);
}